// Round 1
// baseline (231.607 us; speedup 1.0000x reference)
//
#include <hip/hip_runtime.h>
#include <hip/hip_bf16.h>
#include <stdint.h>

// MultiGraphConvLayer: H=3 heads, L=2 layers, B=16, S=512, D=512.
// All heavy math done as bf16 MFMA (16x16x32), fp32 accumulate.
// Workspace usage ~134 MiB (see layout in kernel_launch).

#define HH 3
#define LL 2
#define BB 16
#define SS 512
#define DD 512
#define FF 3072  // HH*LL*DD

typedef __attribute__((ext_vector_type(8))) short bf16x8;
typedef __attribute__((ext_vector_type(4))) float f32x4;
typedef __attribute__((ext_vector_type(4))) float vfloat4;

__device__ __forceinline__ short f2b(float x) {
  union { float f; uint32_t u; } v; v.f = x;
  return (short)((v.u + 0x7FFFu + ((v.u >> 16) & 1u)) >> 16);
}
__device__ __forceinline__ float b2f(short s) {
  union { uint32_t u; float f; } v; v.u = ((uint32_t)(uint16_t)s) << 16;
  return v.f;
}

__device__ __forceinline__ void gld16(const short* g, short* l) {
  __builtin_amdgcn_global_load_lds((const __attribute__((address_space(1))) void*)g,
                                   (__attribute__((address_space(3))) void*)l, 16, 0, 0);
}

// ---- adj fp32 -> bf16, plus rdenom = 1/(rowsum+1). One wave per row of 512.
__global__ void k_cvt_adj(const float* __restrict__ adj, short* __restrict__ adjb,
                          float* __restrict__ rden) {
  int row = blockIdx.x * 4 + (threadIdx.x >> 6);
  int lane = threadIdx.x & 63;
  const float* src = adj + (size_t)row * SS;
  vfloat4 a = *(const vfloat4*)(src + lane * 8);
  vfloat4 b = *(const vfloat4*)(src + lane * 8 + 4);
  bf16x8 o;
  o[0] = f2b(a[0]); o[1] = f2b(a[1]); o[2] = f2b(a[2]); o[3] = f2b(a[3]);
  o[4] = f2b(b[0]); o[5] = f2b(b[1]); o[6] = f2b(b[2]); o[7] = f2b(b[3]);
  *(bf16x8*)(adjb + (size_t)row * SS + lane * 8) = o;
  float s = a[0]+a[1]+a[2]+a[3]+b[0]+b[1]+b[2]+b[3];
  #pragma unroll
  for (int off = 32; off > 0; off >>= 1) s += __shfl_xor(s, off);
  if (lane == 0) rden[row] = 1.0f / (s + 1.0f);
}

// ---- W_gcn and W_out fp32 -> bf16 (both are 1,572,864 elements).
__global__ void k_cvt_w(const float* __restrict__ wg, const float* __restrict__ wo,
                        short* __restrict__ wgb, short* __restrict__ wob) {
  size_t i = ((size_t)blockIdx.x * 256 + threadIdx.x) * 8;
  vfloat4 a = *(const vfloat4*)(wg + i);
  vfloat4 b = *(const vfloat4*)(wg + i + 4);
  bf16x8 o;
  o[0]=f2b(a[0]); o[1]=f2b(a[1]); o[2]=f2b(a[2]); o[3]=f2b(a[3]);
  o[4]=f2b(b[0]); o[5]=f2b(b[1]); o[6]=f2b(b[2]); o[7]=f2b(b[3]);
  *(bf16x8*)(wgb + i) = o;
  a = *(const vfloat4*)(wo + i);
  b = *(const vfloat4*)(wo + i + 4);
  o[0]=f2b(a[0]); o[1]=f2b(a[1]); o[2]=f2b(a[2]); o[3]=f2b(a[3]);
  o[4]=f2b(b[0]); o[5]=f2b(b[1]); o[6]=f2b(b[2]); o[7]=f2b(b[3]);
  *(bf16x8*)(wob + i) = o;
}

// ---- gcn_inputs [B][S][D] fp32 -> X0T [B][D][S] bf16 (64x64 LDS tile transpose)
__global__ void k_t_x0(const float* __restrict__ x, short* __restrict__ xt) {
  __shared__ short t[64][72];
  int bid = blockIdx.x;            // BB*64
  int b = bid >> 6, q = bid & 63;
  int s0 = (q >> 3) * 64, d0 = (q & 7) * 64;
  int tid = threadIdx.x;
  int r = tid >> 4, c4 = (tid & 15) * 4;
  const float* src = x + ((size_t)b * SS + s0) * DD + d0;
  #pragma unroll
  for (int rr = 0; rr < 64; rr += 16) {
    vfloat4 v = *(const vfloat4*)(src + (size_t)(r + rr) * DD + c4);
    t[r+rr][c4+0] = f2b(v[0]); t[r+rr][c4+1] = f2b(v[1]);
    t[r+rr][c4+2] = f2b(v[2]); t[r+rr][c4+3] = f2b(v[3]);
  }
  __syncthreads();
  int dloc = tid >> 3, s8 = (tid & 7) * 8;
  short* dst = xt + (size_t)b * DD * SS + s0;
  #pragma unroll
  for (int dd = 0; dd < 64; dd += 32) {
    bf16x8 o;
    #pragma unroll
    for (int j = 0; j < 8; j++) o[j] = t[s8 + j][dloc + dd];
    *(bf16x8*)(dst + (size_t)(d0 + dloc + dd) * SS + s8) = o;
  }
}

// ---- final slab (layer-0 outputs, bf16, row stride FF) -> YT [H*B][D][S] bf16
__global__ void k_t_y(const short* __restrict__ fin, short* __restrict__ yt) {
  __shared__ short t[64][72];
  int bid = blockIdx.x;            // HH*BB*64
  int hb = bid >> 6, q = bid & 63;
  int h = hb / BB, b = hb % BB;
  int s0 = (q >> 3) * 64, e0 = (q & 7) * 64;
  int tid = threadIdx.x;
  int r = tid >> 3, c8 = (tid & 7) * 8;
  const short* src = fin + ((size_t)b * SS + s0) * FF + (size_t)(h * LL) * DD + e0;
  #pragma unroll
  for (int rr = 0; rr < 64; rr += 32) {
    bf16x8 v = *(const bf16x8*)(src + (size_t)(r + rr) * FF + c8);
    #pragma unroll
    for (int j = 0; j < 8; j++) t[r+rr][c8+j] = v[j];
  }
  __syncthreads();
  int eloc = tid >> 3, s8 = (tid & 7) * 8;
  short* dst = yt + (size_t)hb * DD * SS + s0;
  #pragma unroll
  for (int ee = 0; ee < 64; ee += 32) {
    bf16x8 o;
    #pragma unroll
    for (int j = 0; j < 8; j++) o[j] = t[s8 + j][eloc + ee];
    *(bf16x8*)(dst + (size_t)(e0 + eloc + ee) * SS + s8) = o;
  }
}

// ---- NT GEMM core: C(128x128) = A(128xK, row-major lda) * B'(128xK, row-major ldb)^T
// 4 waves, each a 64x64 quadrant of 4x4 16x16x32 MFMA fragments.
__device__ __forceinline__ void gemm128(const short* __restrict__ A, int lda,
                                        const short* __restrict__ Bm, int ldb,
                                        int K, short* As, short* Bs,
                                        f32x4 acc[4][4]) {
  int tid = threadIdx.x;
  int lane = tid & 63, wid = tid >> 6;
  int wr = wid >> 1, wc = wid & 1;
  int lrow = lane & 15, kg = (lane >> 4) * 8;
  const short* ga = A + (size_t)(tid >> 2) * lda + (tid & 3) * 8;
  const short* gb = Bm + (size_t)(tid >> 2) * ldb + (tid & 3) * 8;
  short* la = As + tid * 8;
  short* lb = Bs + tid * 8;
  for (int k0 = 0; k0 < K; k0 += 32) {
    gld16(ga + k0, la);
    gld16(ga + k0 + (size_t)64 * lda, la + 2048);
    gld16(gb + k0, lb);
    gld16(gb + k0 + (size_t)64 * ldb, lb + 2048);
    asm volatile("s_waitcnt vmcnt(0)" ::: "memory");
    __syncthreads();
    bf16x8 af[4], bv[4];
    #pragma unroll
    for (int m = 0; m < 4; m++)
      af[m] = *(const bf16x8*)(As + (size_t)(wr*64 + m*16 + lrow) * 32 + kg);
    #pragma unroll
    for (int n = 0; n < 4; n++)
      bv[n] = *(const bf16x8*)(Bs + (size_t)(wc*64 + n*16 + lrow) * 32 + kg);
    #pragma unroll
    for (int m = 0; m < 4; m++)
      #pragma unroll
      for (int n = 0; n < 4; n++)
        acc[m][n] = __builtin_amdgcn_mfma_f32_16x16x32_bf16(af[m], bv[n], acc[m][n], 0, 0, 0);
    __syncthreads();
  }
}

// ---- kA: AxpX[hb] = adj_hb @ X_{h,layer} + X   (bf16 out)
__global__ __launch_bounds__(256) void k_gemmA(
    const short* __restrict__ adjb, const short* __restrict__ xtp,
    const float* __restrict__ x0f, const short* __restrict__ finb,
    int layer, short* __restrict__ axpx) {
  __shared__ short lds[8192];
  int bx = blockIdx.x;             // HH*BB*16
  int hb = bx >> 4, q = bx & 15;
  int h = hb / BB, b = hb % BB;
  int tr = q >> 2, tc = q & 3;
  const short* A = adjb + (size_t)hb * SS * SS + (size_t)(tr * 128) * SS;
  const short* Bm = (layer == 0)
      ? xtp + (size_t)b * DD * SS + (size_t)(tc * 128) * SS
      : xtp + (size_t)hb * DD * SS + (size_t)(tc * 128) * SS;
  f32x4 acc[4][4];
  #pragma unroll
  for (int m = 0; m < 4; m++)
    #pragma unroll
    for (int n = 0; n < 4; n++) acc[m][n] = (f32x4){0.f, 0.f, 0.f, 0.f};
  gemm128(A, SS, Bm, SS, SS, lds, lds + 4096, acc);
  int lane = threadIdx.x & 63, wid = threadIdx.x >> 6;
  int wr = wid >> 1, wc = wid & 1;
  int r4 = (lane >> 4) * 4, cn = lane & 15;
  short* outp = axpx + (size_t)hb * SS * DD;
  #pragma unroll
  for (int m = 0; m < 4; m++) {
    #pragma unroll
    for (int n = 0; n < 4; n++) {
      #pragma unroll
      for (int r = 0; r < 4; r++) {
        int s = tr*128 + wr*64 + m*16 + r4 + r;
        int d = tc*128 + wc*64 + n*16 + cn;
        float add = (layer == 0)
            ? x0f[((size_t)b * SS + s) * DD + d]
            : b2f(finb[((size_t)b * SS + s) * FF + (size_t)(h * LL) * DD + d]);
        outp[(size_t)s * DD + d] = f2b(acc[m][n][r] + add);
      }
    }
  }
}

// ---- kB: Y = relu((AxpX @ W^T + 2b) * rdenom) -> final slab (bf16)
__global__ __launch_bounds__(256) void k_gemmB(
    const short* __restrict__ axpx, const short* __restrict__ wgb,
    const float* __restrict__ bg, const float* __restrict__ rden,
    int layer, short* __restrict__ finb) {
  __shared__ short lds[8192];
  int bx = blockIdx.x;             // HH*BB*16
  int hb = bx >> 4, q = bx & 15;
  int h = hb / BB, b = hb % BB;
  int tr = q >> 2, tc = q & 3;
  int idx = h * LL + layer;
  const short* A = axpx + (size_t)hb * SS * DD + (size_t)(tr * 128) * DD;
  const short* Bm = wgb + (size_t)idx * DD * DD + (size_t)(tc * 128) * DD;
  f32x4 acc[4][4];
  #pragma unroll
  for (int m = 0; m < 4; m++)
    #pragma unroll
    for (int n = 0; n < 4; n++) acc[m][n] = (f32x4){0.f, 0.f, 0.f, 0.f};
  gemm128(A, DD, Bm, DD, DD, lds, lds + 4096, acc);
  int lane = threadIdx.x & 63, wid = threadIdx.x >> 6;
  int wr = wid >> 1, wc = wid & 1;
  int r4 = (lane >> 4) * 4, cn = lane & 15;
  #pragma unroll
  for (int m = 0; m < 4; m++) {
    #pragma unroll
    for (int n = 0; n < 4; n++) {
      #pragma unroll
      for (int r = 0; r < 4; r++) {
        int s = tr*128 + wr*64 + m*16 + r4 + r;
        int e = tc*128 + wc*64 + n*16 + cn;
        float v = (acc[m][n][r] + 2.0f * bg[(size_t)idx * DD + e])
                  * rden[(size_t)hb * SS + s];
        v = fmaxf(v, 0.0f);
        finb[((size_t)b * SS + s) * FF + (size_t)idx * DD + e] = f2b(v);
      }
    }
  }
}

// ---- kF: out = gcn_inputs + final @ W_out^T + b_out  (fp32 out)
__global__ __launch_bounds__(256) void k_gemmF(
    const short* __restrict__ finb, const short* __restrict__ wob,
    const float* __restrict__ bo, const float* __restrict__ x0f,
    float* __restrict__ out) {
  __shared__ short lds[8192];
  int bx = blockIdx.x;             // BB*16
  int b = bx >> 4, q = bx & 15;
  int tr = q >> 2, tc = q & 3;
  const short* A = finb + (size_t)b * SS * FF + (size_t)(tr * 128) * FF;
  const short* Bm = wob + (size_t)(tc * 128) * FF;
  f32x4 acc[4][4];
  #pragma unroll
  for (int m = 0; m < 4; m++)
    #pragma unroll
    for (int n = 0; n < 4; n++) acc[m][n] = (f32x4){0.f, 0.f, 0.f, 0.f};
  gemm128(A, FF, Bm, FF, FF, lds, lds + 4096, acc);
  int lane = threadIdx.x & 63, wid = threadIdx.x >> 6;
  int wr = wid >> 1, wc = wid & 1;
  int r4 = (lane >> 4) * 4, cn = lane & 15;
  #pragma unroll
  for (int m = 0; m < 4; m++) {
    #pragma unroll
    for (int n = 0; n < 4; n++) {
      #pragma unroll
      for (int r = 0; r < 4; r++) {
        int s = tr*128 + wr*64 + m*16 + r4 + r;
        int d = tc*128 + wc*64 + n*16 + cn;
        size_t o = ((size_t)b * SS + s) * DD + d;
        out[o] = acc[m][n][r] + bo[d] + x0f[o];
      }
    }
  }
}

extern "C" void kernel_launch(void* const* d_in, const int* in_sizes, int n_in,
                              void* d_out, int out_size, void* d_ws, size_t ws_size,
                              hipStream_t stream) {
  const float* adj = (const float*)d_in[0];
  const float* x0  = (const float*)d_in[1];
  // d_in[2], d_in[3]: mask / domain_mask — unused by the reference forward.
  const float* wg  = (const float*)d_in[4];
  const float* bg  = (const float*)d_in[5];
  const float* wo  = (const float*)d_in[6];
  const float* bo  = (const float*)d_in[7];
  float* out = (float*)d_out;

  char* p = (char*)d_ws;
  short* adjb = (short*)p; p += (size_t)HH*BB*SS*SS*2;   // 25,165,824
  short* x0t  = (short*)p; p += (size_t)BB*DD*SS*2;      //  8,388,608
  short* yt   = (short*)p; p += (size_t)HH*BB*DD*SS*2;   // 25,165,824
  short* axpx = (short*)p; p += (size_t)HH*BB*SS*DD*2;   // 25,165,824
  short* finb = (short*)p; p += (size_t)BB*SS*FF*2;      // 50,331,648
  short* wgb  = (short*)p; p += (size_t)HH*LL*DD*DD*2;   //  3,145,728
  short* wob  = (short*)p; p += (size_t)DD*FF*2;         //  3,145,728
  float* rden = (float*)p;                               //     98,304
  // total ~134.1 MiB of ws

  k_cvt_adj<<<HH*BB*SS/4, 256, 0, stream>>>(adj, adjb, rden);
  k_cvt_w<<<768, 256, 0, stream>>>(wg, wo, wgb, wob);
  k_t_x0<<<BB*64, 256, 0, stream>>>(x0, x0t);

  // layer 0
  k_gemmA<<<HH*BB*16, 256, 0, stream>>>(adjb, x0t, x0, finb, 0, axpx);
  k_gemmB<<<HH*BB*16, 256, 0, stream>>>(axpx, wgb, bg, rden, 0, finb);
  // transpose layer-0 outputs for layer-1 A-operand
  k_t_y<<<HH*BB*64, 256, 0, stream>>>(finb, yt);
  // layer 1
  k_gemmA<<<HH*BB*16, 256, 0, stream>>>(adjb, yt, x0, finb, 1, axpx);
  k_gemmB<<<HH*BB*16, 256, 0, stream>>>(axpx, wgb, bg, rden, 1, finb);
  // output projection + residual
  k_gemmF<<<BB*16, 256, 0, stream>>>(finb, wob, bo, x0, out);
}